// Round 1
// 19742.047 us; speedup vs baseline: 1.1502x; 1.1502x over previous
//
#include <hip/hip_runtime.h>
#include <stdint.h>

#define H      1024
#define FOURH  4096
#define BB     64
#define TT     128
#define NL     2

// floats per pipeline slot of zpart: [2 m][4 kc][B][4H]
#define SLOTSZ ((size_t)2 * 4 * BB * FOURH)

// ---------------- threefry2x32 (bit-exact, Random123-verified) ----------------
__device__ __forceinline__ void tf_round(uint32_t &x0, uint32_t &x1, int r) {
  x0 += x1;
  x1 = (x1 << r) | (x1 >> (32 - r));
  x1 ^= x0;
}

__device__ __forceinline__ void threefry(uint32_t k0, uint32_t k1,
                                         uint32_t c0, uint32_t c1,
                                         uint32_t &o0, uint32_t &o1) {
  uint32_t k2 = k0 ^ k1 ^ 0x1BD11BDAu;
  uint32_t x0 = c0 + k0, x1 = c1 + k1;
  tf_round(x0,x1,13); tf_round(x0,x1,15); tf_round(x0,x1,26); tf_round(x0,x1,6);
  x0 += k1; x1 += k2 + 1u;
  tf_round(x0,x1,17); tf_round(x0,x1,29); tf_round(x0,x1,16); tf_round(x0,x1,24);
  x0 += k2; x1 += k0 + 2u;
  tf_round(x0,x1,13); tf_round(x0,x1,15); tf_round(x0,x1,26); tf_round(x0,x1,6);
  x0 += k0; x1 += k1 + 3u;
  tf_round(x0,x1,17); tf_round(x0,x1,29); tf_round(x0,x1,16); tf_round(x0,x1,24);
  x0 += k1; x1 += k2 + 4u;
  tf_round(x0,x1,13); tf_round(x0,x1,15); tf_round(x0,x1,26); tf_round(x0,x1,6);
  x0 += k2; x1 += k0 + 5u;
  o0 = x0; o1 = x1;
}

// partitionable random_bits (32-bit): element i -> xor of the two output words of ctr (0, i)
__device__ __forceinline__ uint32_t pbits(uint32_t k0, uint32_t k1, uint32_t i) {
  uint32_t o0, o1;
  threefry(k0, k1, 0u, i, o0, o1);
  return o0 ^ o1;
}

// bits -> uniform exactly as jax._uniform(minval=-0.99999994, maxval=1)
__device__ __forceinline__ float u01s(uint32_t bits) {
  float f = __uint_as_float((bits >> 9) | 0x3F800000u) - 1.0f;   // [0,1)
  const float LO = -0.99999994f;
  return fmaxf(LO, f * 2.0f + LO);   // (maxval-minval) ties-to-even to 2.0f
}

// XLA ErfInv32: w = -log1p(-x*x), Giles polynomial
__device__ __forceinline__ float erfinv_(float x) {
  float w = -log1pf(-x * x);
  float p;
  if (w < 5.0f) {
    w = w - 2.5f;
    p = 2.81022636e-08f;
    p = fmaf(p, w, 3.43273939e-07f);
    p = fmaf(p, w, -3.5233877e-06f);
    p = fmaf(p, w, -4.39150654e-06f);
    p = fmaf(p, w, 0.00021858087f);
    p = fmaf(p, w, -0.00125372503f);
    p = fmaf(p, w, -0.00417768164f);
    p = fmaf(p, w, 0.246640727f);
    p = fmaf(p, w, 1.50140941f);
  } else {
    w = sqrtf(w) - 3.0f;
    p = -0.000200214257f;
    p = fmaf(p, w, 0.000100950558f);
    p = fmaf(p, w, 0.00134934322f);
    p = fmaf(p, w, -0.00367342844f);
    p = fmaf(p, w, 0.00573950773f);
    p = fmaf(p, w, -0.0076224613f);
    p = fmaf(p, w, 0.00943887047f);
    p = fmaf(p, w, 1.00167406f);
    p = fmaf(p, w, 2.83297682f);
  }
  return p * x;
}

__device__ __forceinline__ float norm_from_bits(uint32_t bits) {
  return 1.41421356237f * erfinv_(u01s(bits));
}

__device__ __forceinline__ float sigm_(float x) {
  return 1.0f / (1.0f + __expf(-x));
}

__device__ __forceinline__ float tanh_(float x) {
  float ax = fabsf(x);
  float e = __expf(-2.0f * ax);
  float t = (1.0f - e) / (1.0f + e);
  return copysignf(t, x);
}

// ---------------- key chain: key(12345) -> fold_in(t) -> fold_in(l) -> split(4) ----------------
__global__ void keys_kernel(uint32_t* __restrict__ keys) {
  int id = blockIdx.x * blockDim.x + threadIdx.x;
  if (id >= TT * NL) return;
  int t = id >> 1, l = id & 1;
  uint32_t kt0, kt1, ktl0, ktl1;
  threefry(0u, 12345u, 0u, (uint32_t)t, kt0, kt1);
  threefry(kt0, kt1, 0u, (uint32_t)l, ktl0, ktl1);
  uint32_t* o = keys + id * 8;
  threefry(ktl0, ktl1, 0u, 0u, o[0], o[1]);   // k1 -> Wih noise
  threefry(ktl0, ktl1, 0u, 1u, o[2], o[3]);   // k2 -> Whh noise
  threefry(ktl0, ktl1, 0u, 2u, o[4], o[5]);   // k3 -> bih noise
  threefry(ktl0, ktl1, 0u, 3u, o[6], o[7]);   // k4 -> bhh noise
}

// ---------------- fused noise + GEMM, split-K, 2-slot wavefront pipeline ----------------
// Wavefront pipelining over the L=2 layer chain: slot0 = (l=0, t=t0), slot1 = (l=1, t=t1=t0-1)
// are mutually independent, so both run in ONE launch: grid = 1024 blocks = 4 blocks/CU
// (vs 512 = 2/CU before) -> 4 waves/SIMD latency hiding for the threefry/erfinv chains.
// Per-block arithmetic is BIT-IDENTICAL to the previous version (same m/kc/ct decomposition,
// same FMA order), so the output must match the previous absmax exactly.
__global__ __launch_bounds__(256, 3) void gemm_pair_kernel(
    const float* __restrict__ x, const float* __restrict__ h_state,
    const float* __restrict__ w_ih, const float* __restrict__ w_hh,
    const float* __restrict__ b_ih, const float* __restrict__ b_hh,
    const uint32_t* __restrict__ keys,
    float* __restrict__ zpart,       // [2 slots][2][4][B][4096]
    int t0, int en0, int t1, int en1)
{
  int slot = blockIdx.x >> 9;          // 0: (l=0,t0)   1: (l=1,t1)
  if (!(slot ? en1 : en0)) return;
  int l   = slot;
  int t   = slot ? t1 : t0;
  int wg  = blockIdx.x & 511;
  int m   = wg & 1;
  int kc  = (wg >> 1) & 3;
  int ct  = wg >> 3;           // 0..63
  int g0  = ct * 64;
  int d0k = kc * 256;

  const float* A = (m == 0) ? ((l == 0) ? (x + (size_t)t * (BB * H)) : h_state)
                            : (h_state + (size_t)l * (BB * H));
  const float* W = ((m == 0) ? w_ih : w_hh) + (size_t)l * (FOURH * H);
  const uint32_t* kk = keys + ((size_t)t * NL + l) * 8;
  uint32_t wk0 = kk[m * 2], wk1 = kk[m * 2 + 1];

  __shared__ float4 At4[64][17];
  __shared__ float4 Wt4[64][17];
  __shared__ float  biasn[64];

  int tid = threadIdx.x;
  float acc[4][4] = {{0.f,0.f,0.f,0.f},{0.f,0.f,0.f,0.f},{0.f,0.f,0.f,0.f},{0.f,0.f,0.f,0.f}};
  int b0r = (tid >> 4) * 4;
  int c0r = (tid & 15) * 4;

  for (int s = 0; s < 4; ++s) {
    int d0 = d0k + s * 64;
    #pragma unroll
    for (int i = 0; i < 4; ++i) {
      int lin = i * 256 + tid;       // 0..1023
      int r   = lin >> 4;
      int d4  = lin & 15;
      At4[r][d4] = *(const float4*)(A + (size_t)r * H + d0 + d4 * 4);
      // stage noisy W: element (g, d) -> flat i = g*1024 + d, noise = N(key, i)
      int g = g0 + r;
      int d = d0 + d4 * 4;
      float4 wv = *(const float4*)(W + (size_t)g * H + d);
      uint32_t ibase = (uint32_t)(g * H + d);
      wv.x = fmaf(0.1f, norm_from_bits(pbits(wk0, wk1, ibase + 0u)), wv.x);
      wv.y = fmaf(0.1f, norm_from_bits(pbits(wk0, wk1, ibase + 1u)), wv.y);
      wv.z = fmaf(0.1f, norm_from_bits(pbits(wk0, wk1, ibase + 2u)), wv.z);
      wv.w = fmaf(0.1f, norm_from_bits(pbits(wk0, wk1, ibase + 3u)), wv.w);
      Wt4[r][d4] = wv;
    }
    __syncthreads();
    #pragma unroll
    for (int db = 0; db < 16; ++db) {
      float4 aa[4], ww[4];
      #pragma unroll
      for (int i = 0; i < 4; ++i) { aa[i] = At4[b0r + i][db]; ww[i] = Wt4[c0r + i][db]; }
      #pragma unroll
      for (int i = 0; i < 4; ++i)
        #pragma unroll
        for (int j = 0; j < 4; ++j) {
          acc[i][j] = fmaf(aa[i].x, ww[j].x, acc[i][j]);
          acc[i][j] = fmaf(aa[i].y, ww[j].y, acc[i][j]);
          acc[i][j] = fmaf(aa[i].z, ww[j].z, acc[i][j]);
          acc[i][j] = fmaf(aa[i].w, ww[j].w, acc[i][j]);
        }
    }
    __syncthreads();
  }

  // noisy bias folded into the kc==0 partial
  if (kc == 0) {
    if (tid < 64) {
      int g = g0 + tid;
      const float* bias = ((m == 0) ? b_ih : b_hh) + (size_t)l * FOURH;
      uint32_t bk0 = kk[4 + m * 2], bk1 = kk[5 + m * 2];
      biasn[tid] = fmaf(0.1f, norm_from_bits(pbits(bk0, bk1, (uint32_t)g)), bias[g]);
    }
    __syncthreads();
  }

  float* zp = zpart + (size_t)slot * SLOTSZ + (size_t)((m * 4 + kc) * BB) * FOURH;
  #pragma unroll
  for (int i = 0; i < 4; ++i) {
    int b = b0r + i;
    float4 v = make_float4(acc[i][0], acc[i][1], acc[i][2], acc[i][3]);
    if (kc == 0) {
      v.x += biasn[c0r + 0]; v.y += biasn[c0r + 1];
      v.z += biasn[c0r + 2]; v.w += biasn[c0r + 3];
    }
    *(float4*)(zp + (size_t)b * FOURH + g0 + c0r) = v;
  }
}

// ---------------- reduce split-K, dual LN, gates, cell update, LN(c) ----------------
// Paired across the same two pipeline slots: 128 blocks (vs 64 before).
// Per-block arithmetic bit-identical to the previous version.
__device__ __forceinline__ float block_sum1024(float v, float* red) {
  #pragma unroll
  for (int o = 32; o > 0; o >>= 1) v += __shfl_down(v, o);
  int wid = threadIdx.x >> 6;
  __syncthreads();
  if ((threadIdx.x & 63) == 0) red[wid] = v;
  __syncthreads();
  float s = 0.f;
  #pragma unroll
  for (int i = 0; i < 16; ++i) s += red[i];
  return s;
}

__global__ __launch_bounds__(1024) void cell_pair_kernel(
    const float* __restrict__ zpart,
    const float* __restrict__ ln_ih_w, const float* __restrict__ ln_ih_b,
    const float* __restrict__ ln_hh_w, const float* __restrict__ ln_hh_b,
    const float* __restrict__ ln_ho_w, const float* __restrict__ ln_ho_b,
    float* __restrict__ h_state, float* __restrict__ c_state,
    float* __restrict__ y,          // base of y [T][B][H]
    int t0, int en0, int t1, int en1)
{
  int slot = blockIdx.x >> 6;          // 0: (l=0,t0)   1: (l=1,t1)
  if (!(slot ? en1 : en0)) return;
  int l = slot;
  int b = blockIdx.x & 63;
  int tid = threadIdx.x;
  const float* zsl = zpart + (size_t)slot * SLOTSZ;
  __shared__ float red[16];
  __shared__ float G[FOURH];

  float zih[4], zhh[4];
  float s_ih = 0.f, s_hh = 0.f;
  #pragma unroll
  for (int k = 0; k < 4; ++k) {
    int g = k * 1024 + tid;
    float a = 0.f, c = 0.f;
    #pragma unroll
    for (int kc = 0; kc < 4; ++kc) {
      a += zsl[(size_t)((0 * 4 + kc) * BB + b) * FOURH + g];
      c += zsl[(size_t)((1 * 4 + kc) * BB + b) * FOURH + g];
    }
    zih[k] = a; zhh[k] = c;
    s_ih += a; s_hh += c;
  }
  float mu_ih = block_sum1024(s_ih, red) * (1.0f / 4096.0f);
  float mu_hh = block_sum1024(s_hh, red) * (1.0f / 4096.0f);
  float v_ih = 0.f, v_hh = 0.f;
  #pragma unroll
  for (int k = 0; k < 4; ++k) {
    float d1 = zih[k] - mu_ih; v_ih += d1 * d1;
    float d2 = zhh[k] - mu_hh; v_hh += d2 * d2;
  }
  v_ih = block_sum1024(v_ih, red) * (1.0f / 4096.0f);
  v_hh = block_sum1024(v_hh, red) * (1.0f / 4096.0f);
  float r_ih = rsqrtf(v_ih + 1e-5f);
  float r_hh = rsqrtf(v_hh + 1e-5f);

  const float* liw = ln_ih_w + (size_t)l * FOURH;
  const float* lib = ln_ih_b + (size_t)l * FOURH;
  const float* lhw = ln_hh_w + (size_t)l * FOURH;
  const float* lhb = ln_hh_b + (size_t)l * FOURH;
  #pragma unroll
  for (int k = 0; k < 4; ++k) {
    int g = k * 1024 + tid;
    G[g] = fmaf((zih[k] - mu_ih) * r_ih, liw[g], lib[g])
         + fmaf((zhh[k] - mu_hh) * r_hh, lhw[g], lhb[g]);
  }
  __syncthreads();

  int j = tid;   // 1024 threads <-> 1024 cell elements
  float ig = sigm_(G[j]);
  float fg = sigm_(G[j + 1024]);
  float oo = sigm_(G[j + 2048]);
  float gg = tanh_(G[j + 3072]);
  float cold = c_state[(size_t)(l * BB + b) * H + j];
  float c2 = fmaf(fg, cold, ig * gg);

  float mu_c = block_sum1024(c2, red) * (1.0f / 1024.0f);
  float dc = c2 - mu_c;
  float vc = block_sum1024(dc * dc, red) * (1.0f / 1024.0f);
  float r_c = rsqrtf(vc + 1e-5f);

  float lnc = fmaf((c2 - mu_c) * r_c, ln_ho_w[(size_t)l * H + j], ln_ho_b[(size_t)l * H + j]);
  float hn = oo * tanh_(lnc);
  c_state[(size_t)(l * BB + b) * H + j] = c2;
  h_state[(size_t)(l * BB + b) * H + j] = hn;
  if (l == 1) y[(size_t)t1 * (BB * H) + (size_t)b * H + j] = hn;
}

__global__ void copy_states_kernel(const float* __restrict__ h_state,
                                   const float* __restrict__ c_state,
                                   float* __restrict__ out) {
  int i = blockIdx.x * blockDim.x + threadIdx.x;   // 0..131071
  const size_t YSZ = (size_t)TT * BB * H;
  out[YSZ + i] = h_state[i];
  out[YSZ + (size_t)NL * BB * H + i] = c_state[i];
}

// ---------------- launch ----------------
// Wavefront pipeline over (t, l): phase k runs (l=0, t=k) and (l=1, t=k-1) together.
// Dependencies: l0[k] needs h0[k-1] (cell of phase k-1); l1[k-1] needs h0[k-1], h1[k-2]
// (both from phase k-1's cell). Slots write disjoint zpart halves and disjoint l-states.
extern "C" void kernel_launch(void* const* d_in, const int* in_sizes, int n_in,
                              void* d_out, int out_size, void* d_ws, size_t ws_size,
                              hipStream_t stream) {
  (void)in_sizes; (void)n_in; (void)out_size; (void)ws_size;
  const float* x        = (const float*)d_in[0];
  const float* w_ih     = (const float*)d_in[1];
  const float* w_hh     = (const float*)d_in[2];
  const float* b_ih     = (const float*)d_in[3];
  const float* b_hh     = (const float*)d_in[4];
  const float* ln_ih_w  = (const float*)d_in[5];
  const float* ln_ih_b  = (const float*)d_in[6];
  const float* ln_hh_w  = (const float*)d_in[7];
  const float* ln_hh_b  = (const float*)d_in[8];
  const float* ln_ho_w  = (const float*)d_in[9];
  const float* ln_ho_b  = (const float*)d_in[10];
  float* out = (float*)d_out;

  char* ws = (char*)d_ws;
  uint32_t* keys   = (uint32_t*)ws;                       // 8 KB
  float* h_state   = (float*)(ws + 8192);                 // [2][64][1024]
  float* c_state   = h_state + NL * BB * H;               // [2][64][1024]
  float* zpart     = c_state + NL * BB * H;               // [2 slots][2][4][64][4096] = 16 MB

  keys_kernel<<<1, 256, 0, stream>>>(keys);
  hipMemsetAsync(h_state, 0, (size_t)2 * NL * BB * H * sizeof(float), stream);

  for (int k = 0; k <= TT; ++k) {
    int en0 = (k < TT) ? 1 : 0;
    int en1 = (k >= 1) ? 1 : 0;
    gemm_pair_kernel<<<1024, 256, 0, stream>>>(x, h_state, w_ih, w_hh, b_ih, b_hh,
                                               keys, zpart, k, en0, k - 1, en1);
    cell_pair_kernel<<<128, 1024, 0, stream>>>(zpart,
                                               ln_ih_w, ln_ih_b, ln_hh_w, ln_hh_b,
                                               ln_ho_w, ln_ho_b,
                                               h_state, c_state, out,
                                               k, en0, k - 1, en1);
  }
  copy_states_kernel<<<512, 256, 0, stream>>>(h_state, c_state, out);
}

// Round 2
// 15095.021 us; speedup vs baseline: 1.5043x; 1.3079x over previous
//
#include <hip/hip_runtime.h>
#include <stdint.h>

#define H      1024
#define FOURH  4096
#define BB     64
#define TT     128
#define NL     2

// floats per pipeline slot of zpart: [2 m][4 kc][B][4H]
#define SLOTSZ ((size_t)2 * 4 * BB * FOURH)

// ---------------- threefry2x32 (bit-exact, Random123-verified) ----------------
__device__ __forceinline__ void tf_round(uint32_t &x0, uint32_t &x1, int r) {
  x0 += x1;
  x1 = (x1 << r) | (x1 >> (32 - r));
  x1 ^= x0;
}

__device__ __forceinline__ void threefry(uint32_t k0, uint32_t k1,
                                         uint32_t c0, uint32_t c1,
                                         uint32_t &o0, uint32_t &o1) {
  uint32_t k2 = k0 ^ k1 ^ 0x1BD11BDAu;
  uint32_t x0 = c0 + k0, x1 = c1 + k1;
  tf_round(x0,x1,13); tf_round(x0,x1,15); tf_round(x0,x1,26); tf_round(x0,x1,6);
  x0 += k1; x1 += k2 + 1u;
  tf_round(x0,x1,17); tf_round(x0,x1,29); tf_round(x0,x1,16); tf_round(x0,x1,24);
  x0 += k2; x1 += k0 + 2u;
  tf_round(x0,x1,13); tf_round(x0,x1,15); tf_round(x0,x1,26); tf_round(x0,x1,6);
  x0 += k0; x1 += k1 + 3u;
  tf_round(x0,x1,17); tf_round(x0,x1,29); tf_round(x0,x1,16); tf_round(x0,x1,24);
  x0 += k1; x1 += k2 + 4u;
  tf_round(x0,x1,13); tf_round(x0,x1,15); tf_round(x0,x1,26); tf_round(x0,x1,6);
  x0 += k2; x1 += k0 + 5u;
  o0 = x0; o1 = x1;
}

// partitionable random_bits (32-bit): element i -> xor of the two output words of ctr (0, i)
__device__ __forceinline__ uint32_t pbits(uint32_t k0, uint32_t k1, uint32_t i) {
  uint32_t o0, o1;
  threefry(k0, k1, 0u, i, o0, o1);
  return o0 ^ o1;
}

// bits -> uniform exactly as jax._uniform(minval=-0.99999994, maxval=1)
__device__ __forceinline__ float u01s(uint32_t bits) {
  float f = __uint_as_float((bits >> 9) | 0x3F800000u) - 1.0f;   // [0,1)
  const float LO = -0.99999994f;
  return fmaxf(LO, f * 2.0f + LO);   // (maxval-minval) ties-to-even to 2.0f
}

// XLA ErfInv32: w = -log1p(-x*x), Giles polynomial
__device__ __forceinline__ float erfinv_(float x) {
  float w = -log1pf(-x * x);
  float p;
  if (w < 5.0f) {
    w = w - 2.5f;
    p = 2.81022636e-08f;
    p = fmaf(p, w, 3.43273939e-07f);
    p = fmaf(p, w, -3.5233877e-06f);
    p = fmaf(p, w, -4.39150654e-06f);
    p = fmaf(p, w, 0.00021858087f);
    p = fmaf(p, w, -0.00125372503f);
    p = fmaf(p, w, -0.00417768164f);
    p = fmaf(p, w, 0.246640727f);
    p = fmaf(p, w, 1.50140941f);
  } else {
    w = sqrtf(w) - 3.0f;
    p = -0.000200214257f;
    p = fmaf(p, w, 0.000100950558f);
    p = fmaf(p, w, 0.00134934322f);
    p = fmaf(p, w, -0.00367342844f);
    p = fmaf(p, w, 0.00573950773f);
    p = fmaf(p, w, -0.0076224613f);
    p = fmaf(p, w, 0.00943887047f);
    p = fmaf(p, w, 1.00167406f);
    p = fmaf(p, w, 2.83297682f);
  }
  return p * x;
}

__device__ __forceinline__ float norm_from_bits(uint32_t bits) {
  return 1.41421356237f * erfinv_(u01s(bits));
}

__device__ __forceinline__ float sigm_(float x) {
  return 1.0f / (1.0f + __expf(-x));
}

__device__ __forceinline__ float tanh_(float x) {
  float ax = fabsf(x);
  float e = __expf(-2.0f * ax);
  float t = (1.0f - e) / (1.0f + e);
  return copysignf(t, x);
}

// ---------------- key chain: key(12345) -> fold_in(t) -> fold_in(l) -> split(4) ----------------
__global__ void keys_kernel(uint32_t* __restrict__ keys) {
  int id = blockIdx.x * blockDim.x + threadIdx.x;
  if (id >= TT * NL) return;
  int t = id >> 1, l = id & 1;
  uint32_t kt0, kt1, ktl0, ktl1;
  threefry(0u, 12345u, 0u, (uint32_t)t, kt0, kt1);
  threefry(kt0, kt1, 0u, (uint32_t)l, ktl0, ktl1);
  uint32_t* o = keys + id * 8;
  threefry(ktl0, ktl1, 0u, 0u, o[0], o[1]);   // k1 -> Wih noise
  threefry(ktl0, ktl1, 0u, 1u, o[2], o[3]);   // k2 -> Whh noise
  threefry(ktl0, ktl1, 0u, 2u, o[4], o[5]);   // k3 -> bih noise
  threefry(ktl0, ktl1, 0u, 3u, o[6], o[7]);   // k4 -> bhh noise
}

// ---------------- fused noise + GEMM, split-K, 2-slot wavefront pipeline ----------------
// Wavefront pipelining over the L=2 layer chain: slot0 = (l=0, t=t0), slot1 = (l=1, t=t1=t0-1).
//
// Bank-conflict note (this round's change): W-tile rows are read at a per-lane row
// stride; with row stride 17 float4 (=68 dwords), a 4-row lane stride lands all 16
// lanes on bank-starts {0,16} (8-way conflict). Columns are therefore distributed
// among threads STRIDED: thread (tid&15) owns columns (tid&15)+16j, j=0..3, so ww
// lanes read CONSECUTIVE rows -> bank starts 4*l mod 32 = {0,4,...,28} (2 addrs per
// start = 2-way = free). Per-output accumulation order is unchanged -> zpart is
// bit-identical to the previous version (absmax must not move).
__global__ __launch_bounds__(256, 3) void gemm_pair_kernel(
    const float* __restrict__ x, const float* __restrict__ h_state,
    const float* __restrict__ w_ih, const float* __restrict__ w_hh,
    const float* __restrict__ b_ih, const float* __restrict__ b_hh,
    const uint32_t* __restrict__ keys,
    float* __restrict__ zpart,       // [2 slots][2][4][B][4096]
    int t0, int en0, int t1, int en1)
{
  int slot = blockIdx.x >> 9;          // 0: (l=0,t0)   1: (l=1,t1)
  if (!(slot ? en1 : en0)) return;
  int l   = slot;
  int t   = slot ? t1 : t0;
  int wg  = blockIdx.x & 511;
  int m   = wg & 1;
  int kc  = (wg >> 1) & 3;
  int ct  = wg >> 3;           // 0..63
  int g0  = ct * 64;
  int d0k = kc * 256;

  const float* A = (m == 0) ? ((l == 0) ? (x + (size_t)t * (BB * H)) : h_state)
                            : (h_state + (size_t)l * (BB * H));
  const float* W = ((m == 0) ? w_ih : w_hh) + (size_t)l * (FOURH * H);
  const uint32_t* kk = keys + ((size_t)t * NL + l) * 8;
  uint32_t wk0 = kk[m * 2], wk1 = kk[m * 2 + 1];

  __shared__ float4 At4[64][17];
  __shared__ float4 Wt4[64][17];
  __shared__ float  biasn[64];

  int tid = threadIdx.x;
  float acc[4][4] = {{0.f,0.f,0.f,0.f},{0.f,0.f,0.f,0.f},{0.f,0.f,0.f,0.f},{0.f,0.f,0.f,0.f}};
  int b0r = (tid >> 4) * 4;     // 4 consecutive batch rows
  int c0  = tid & 15;           // columns c0 + 16j  (strided -> conflict-free ww reads)

  for (int s = 0; s < 4; ++s) {
    int d0 = d0k + s * 64;
    #pragma unroll
    for (int i = 0; i < 4; ++i) {
      int lin = i * 256 + tid;       // 0..1023
      int r   = lin >> 4;
      int d4  = lin & 15;
      At4[r][d4] = *(const float4*)(A + (size_t)r * H + d0 + d4 * 4);
      // stage noisy W: element (g, d) -> flat i = g*1024 + d, noise = N(key, i)
      int g = g0 + r;
      int d = d0 + d4 * 4;
      float4 wv = *(const float4*)(W + (size_t)g * H + d);
      uint32_t ibase = (uint32_t)(g * H + d);
      wv.x = fmaf(0.1f, norm_from_bits(pbits(wk0, wk1, ibase + 0u)), wv.x);
      wv.y = fmaf(0.1f, norm_from_bits(pbits(wk0, wk1, ibase + 1u)), wv.y);
      wv.z = fmaf(0.1f, norm_from_bits(pbits(wk0, wk1, ibase + 2u)), wv.z);
      wv.w = fmaf(0.1f, norm_from_bits(pbits(wk0, wk1, ibase + 3u)), wv.w);
      Wt4[r][d4] = wv;
    }
    __syncthreads();
    #pragma unroll
    for (int db = 0; db < 16; ++db) {
      float4 aa[4], ww[4];
      #pragma unroll
      for (int i = 0; i < 4; ++i) { aa[i] = At4[b0r + i][db]; ww[i] = Wt4[c0 + 16 * i][db]; }
      #pragma unroll
      for (int i = 0; i < 4; ++i)
        #pragma unroll
        for (int j = 0; j < 4; ++j) {
          acc[i][j] = fmaf(aa[i].x, ww[j].x, acc[i][j]);
          acc[i][j] = fmaf(aa[i].y, ww[j].y, acc[i][j]);
          acc[i][j] = fmaf(aa[i].z, ww[j].z, acc[i][j]);
          acc[i][j] = fmaf(aa[i].w, ww[j].w, acc[i][j]);
        }
    }
    __syncthreads();
  }

  // noisy bias folded into the kc==0 partial
  if (kc == 0) {
    if (tid < 64) {
      int g = g0 + tid;
      const float* bias = ((m == 0) ? b_ih : b_hh) + (size_t)l * FOURH;
      uint32_t bk0 = kk[4 + m * 2], bk1 = kk[5 + m * 2];
      biasn[tid] = fmaf(0.1f, norm_from_bits(pbits(bk0, bk1, (uint32_t)g)), bias[g]);
    }
    __syncthreads();
  }

  float* zp = zpart + (size_t)slot * SLOTSZ + (size_t)((m * 4 + kc) * BB) * FOURH;
  #pragma unroll
  for (int i = 0; i < 4; ++i) {
    int b = b0r + i;
    #pragma unroll
    for (int j = 0; j < 4; ++j) {
      float v = acc[i][j];
      if (kc == 0) v += biasn[c0 + 16 * j];
      zp[(size_t)b * FOURH + g0 + c0 + 16 * j] = v;
    }
  }
}

// ---------------- reduce split-K, dual LN, gates, cell update, LN(c) ----------------
__device__ __forceinline__ float block_sum1024(float v, float* red) {
  #pragma unroll
  for (int o = 32; o > 0; o >>= 1) v += __shfl_down(v, o);
  int wid = threadIdx.x >> 6;
  __syncthreads();
  if ((threadIdx.x & 63) == 0) red[wid] = v;
  __syncthreads();
  float s = 0.f;
  #pragma unroll
  for (int i = 0; i < 16; ++i) s += red[i];
  return s;
}

__global__ __launch_bounds__(1024) void cell_pair_kernel(
    const float* __restrict__ zpart,
    const float* __restrict__ ln_ih_w, const float* __restrict__ ln_ih_b,
    const float* __restrict__ ln_hh_w, const float* __restrict__ ln_hh_b,
    const float* __restrict__ ln_ho_w, const float* __restrict__ ln_ho_b,
    float* __restrict__ h_state, float* __restrict__ c_state,
    float* __restrict__ y,          // base of y [T][B][H]
    int t0, int en0, int t1, int en1)
{
  int slot = blockIdx.x >> 6;          // 0: (l=0,t0)   1: (l=1,t1)
  if (!(slot ? en1 : en0)) return;
  int l = slot;
  int b = blockIdx.x & 63;
  int tid = threadIdx.x;
  const float* zsl = zpart + (size_t)slot * SLOTSZ;
  __shared__ float red[16];
  __shared__ float G[FOURH];

  float zih[4], zhh[4];
  float s_ih = 0.f, s_hh = 0.f;
  #pragma unroll
  for (int k = 0; k < 4; ++k) {
    int g = k * 1024 + tid;
    float a = 0.f, c = 0.f;
    #pragma unroll
    for (int kc = 0; kc < 4; ++kc) {
      a += zsl[(size_t)((0 * 4 + kc) * BB + b) * FOURH + g];
      c += zsl[(size_t)((1 * 4 + kc) * BB + b) * FOURH + g];
    }
    zih[k] = a; zhh[k] = c;
    s_ih += a; s_hh += c;
  }
  float mu_ih = block_sum1024(s_ih, red) * (1.0f / 4096.0f);
  float mu_hh = block_sum1024(s_hh, red) * (1.0f / 4096.0f);
  float v_ih = 0.f, v_hh = 0.f;
  #pragma unroll
  for (int k = 0; k < 4; ++k) {
    float d1 = zih[k] - mu_ih; v_ih += d1 * d1;
    float d2 = zhh[k] - mu_hh; v_hh += d2 * d2;
  }
  v_ih = block_sum1024(v_ih, red) * (1.0f / 4096.0f);
  v_hh = block_sum1024(v_hh, red) * (1.0f / 4096.0f);
  float r_ih = rsqrtf(v_ih + 1e-5f);
  float r_hh = rsqrtf(v_hh + 1e-5f);

  const float* liw = ln_ih_w + (size_t)l * FOURH;
  const float* lib = ln_ih_b + (size_t)l * FOURH;
  const float* lhw = ln_hh_w + (size_t)l * FOURH;
  const float* lhb = ln_hh_b + (size_t)l * FOURH;
  #pragma unroll
  for (int k = 0; k < 4; ++k) {
    int g = k * 1024 + tid;
    G[g] = fmaf((zih[k] - mu_ih) * r_ih, liw[g], lib[g])
         + fmaf((zhh[k] - mu_hh) * r_hh, lhw[g], lhb[g]);
  }
  __syncthreads();

  int j = tid;   // 1024 threads <-> 1024 cell elements
  float ig = sigm_(G[j]);
  float fg = sigm_(G[j + 1024]);
  float oo = sigm_(G[j + 2048]);
  float gg = tanh_(G[j + 3072]);
  float cold = c_state[(size_t)(l * BB + b) * H + j];
  float c2 = fmaf(fg, cold, ig * gg);

  float mu_c = block_sum1024(c2, red) * (1.0f / 1024.0f);
  float dc = c2 - mu_c;
  float vc = block_sum1024(dc * dc, red) * (1.0f / 1024.0f);
  float r_c = rsqrtf(vc + 1e-5f);

  float lnc = fmaf((c2 - mu_c) * r_c, ln_ho_w[(size_t)l * H + j], ln_ho_b[(size_t)l * H + j]);
  float hn = oo * tanh_(lnc);
  c_state[(size_t)(l * BB + b) * H + j] = c2;
  h_state[(size_t)(l * BB + b) * H + j] = hn;
  if (l == 1) y[(size_t)t1 * (BB * H) + (size_t)b * H + j] = hn;
}

__global__ void copy_states_kernel(const float* __restrict__ h_state,
                                   const float* __restrict__ c_state,
                                   float* __restrict__ out) {
  int i = blockIdx.x * blockDim.x + threadIdx.x;   // 0..131071
  const size_t YSZ = (size_t)TT * BB * H;
  out[YSZ + i] = h_state[i];
  out[YSZ + (size_t)NL * BB * H + i] = c_state[i];
}

// ---------------- launch ----------------
extern "C" void kernel_launch(void* const* d_in, const int* in_sizes, int n_in,
                              void* d_out, int out_size, void* d_ws, size_t ws_size,
                              hipStream_t stream) {
  (void)in_sizes; (void)n_in; (void)out_size; (void)ws_size;
  const float* x        = (const float*)d_in[0];
  const float* w_ih     = (const float*)d_in[1];
  const float* w_hh     = (const float*)d_in[2];
  const float* b_ih     = (const float*)d_in[3];
  const float* b_hh     = (const float*)d_in[4];
  const float* ln_ih_w  = (const float*)d_in[5];
  const float* ln_ih_b  = (const float*)d_in[6];
  const float* ln_hh_w  = (const float*)d_in[7];
  const float* ln_hh_b  = (const float*)d_in[8];
  const float* ln_ho_w  = (const float*)d_in[9];
  const float* ln_ho_b  = (const float*)d_in[10];
  float* out = (float*)d_out;

  char* ws = (char*)d_ws;
  uint32_t* keys   = (uint32_t*)ws;                       // 8 KB
  float* h_state   = (float*)(ws + 8192);                 // [2][64][1024]
  float* c_state   = h_state + NL * BB * H;               // [2][64][1024]
  float* zpart     = c_state + NL * BB * H;               // [2 slots][2][4][64][4096] = 16 MB

  keys_kernel<<<1, 256, 0, stream>>>(keys);
  hipMemsetAsync(h_state, 0, (size_t)2 * NL * BB * H * sizeof(float), stream);

  for (int k = 0; k <= TT; ++k) {
    int en0 = (k < TT) ? 1 : 0;
    int en1 = (k >= 1) ? 1 : 0;
    gemm_pair_kernel<<<1024, 256, 0, stream>>>(x, h_state, w_ih, w_hh, b_ih, b_hh,
                                               keys, zpart, k, en0, k - 1, en1);
    cell_pair_kernel<<<128, 1024, 0, stream>>>(zpart,
                                               ln_ih_w, ln_ih_b, ln_hh_w, ln_hh_b,
                                               ln_ho_w, ln_ho_b,
                                               h_state, c_state, out,
                                               k, en0, k - 1, en1);
  }
  copy_states_kernel<<<512, 256, 0, stream>>>(h_state, c_state, out);
}